// Round 4
// baseline (529.812 us; speedup 1.0000x reference)
//
#include <hip/hip_runtime.h>

// Problem constants (from reference)
#define VOCAB   20000
#define GLOVE   300
#define C4      75            // GLOVE/4 float4 groups per 300-col row
#define RTOT    16            // 2*TOP_K rows of 300 per vocab entry
#define OUTC    100
#define NLAB    8
#define NOUT    4096          // B*L
#define FT_ROW  (RTOT * GLOVE)   // 4800 floats per vocab entry
#define ROWS_A  16            // vocab rows per block in reduce kernel
#define NITEM   (ROWS_A * C4) // 1200 work items per block

typedef float v4f __attribute__((ext_vector_type(4)));

// ---------------------------------------------------------------------------
// K1: scatter flags (=1) for referenced vocab rows, zero the compact counter,
//     and transpose W[100][300] -> Wtg[75][100] float4 groups.
// No memset needed: ws poison is 0xAAAAAAAA != 1, and false-positive flags
// are harmless (extra proj row computed, never read by k_gather).
// ---------------------------------------------------------------------------
__global__ __launch_bounds__(256) void k_flags(const int* __restrict__ labels,
                                               int* __restrict__ flags,
                                               int* __restrict__ count,
                                               const float4* __restrict__ W4,
                                               float4* __restrict__ Wtg, int n) {
    const int i = blockIdx.x * 256 + threadIdx.x;
    if (i == 0) *count = 0;               // stream-ordered before k_compact
    if (i < n) flags[labels[i]] = 1;
    if (i < C4 * OUTC) {
        const int g = i / OUTC, o = i - g * OUTC;
        Wtg[i] = W4[(size_t)o * C4 + g];
    }
}

// ---------------------------------------------------------------------------
// K2: stream-compact touched vocab rows into list[] (order irrelevant).
// One atomic per wave (ballot-aggregated).
// ---------------------------------------------------------------------------
__global__ __launch_bounds__(256) void k_compact(const int* __restrict__ flags,
                                                 int* __restrict__ list,
                                                 int* __restrict__ count) {
    const int i = blockIdx.x * 256 + threadIdx.x;
    const int lane = threadIdx.x & 63;
    const bool on = (i < VOCAB) && (flags[i] == 1);
    const unsigned long long m = __ballot(on);
    int base = 0;
    if (lane == 0 && m) base = atomicAdd(count, (int)__popcll(m));
    base = __shfl(base, 0);
    if (on) {
        const int off = (int)__popcll(m & ((1ull << lane) - 1ull));
        list[base + off] = i;
    }
}

// ---------------------------------------------------------------------------
// K3 (the big one): for each touched vocab row v = list[...]:
//   rowsum[c] = sum_{r<16} ft[v][r*300 + c]          (phase 1, LDS)
//   proj[v][o] = sum_c rowsum[c] * W[o][c]           (phase 2)
// Block = 256 threads, 16 list entries. LDS = 19.2 KB -> 8 blocks/CU.
// Tail entries duplicate list[count-1] (benign identical-value races).
// Plain (cached) loads this round: A/B test vs nontemporal.
// ---------------------------------------------------------------------------
__global__ __launch_bounds__(256) void k_reduce_proj(const float* __restrict__ ft,
                                                     const float4* __restrict__ Wtg,
                                                     const int* __restrict__ list,
                                                     const int* __restrict__ count,
                                                     float* __restrict__ proj) {
    __shared__ float lds[ROWS_A * GLOVE];
    __shared__ int svrows[ROWS_A];
    const int cnt = *count;
    const int lbase = blockIdx.x * ROWS_A;
    if (lbase >= cnt) return;
    const int tid = threadIdx.x;

    if (tid < ROWS_A) {
        const int idx = lbase + tid;
        svrows[tid] = list[(idx < cnt) ? idx : (cnt - 1)];
    }
    __syncthreads();

    // ---- phase 1: global -> LDS rowsum, coalesced float4 ----
    for (int i = tid; i < NITEM; i += 256) {
        const int r  = i / C4;         // local row slot 0..15
        const int cg = i - r * C4;     // float4 column group 0..74
        const int v  = svrows[r];
        const v4f* p = reinterpret_cast<const v4f*>(
            ft + (size_t)v * FT_ROW + (size_t)cg * 4);
        v4f s = {0.f, 0.f, 0.f, 0.f};
        #pragma unroll
        for (int k = 0; k < RTOT; ++k) {
            s += p[k * C4];            // stride 300 floats between sub-rows
        }
        reinterpret_cast<v4f*>(lds)[i] = s;
    }
    __syncthreads();

    // ---- phase 2: [16 x 300] @ Wt -> [16 x 100] ----
    const int wave = tid >> 6;
    const int lane = tid & 63;
    const int r0 = wave * 4;
    const int o0 = lane;                       // 0..63, always valid (<100)
    const int o1 = lane + 64;                  // 64..127, valid if <100
    const int o1c = (o1 < OUTC) ? o1 : (OUTC - 1);

    float acc0[4] = {0.f, 0.f, 0.f, 0.f};
    float acc1[4] = {0.f, 0.f, 0.f, 0.f};
    const v4f* L4 = reinterpret_cast<const v4f*>(lds);

    for (int g = 0; g < C4; ++g) {
        const float4 w0 = Wtg[g * OUTC + o0];   // coalesced across lanes
        const float4 w1 = Wtg[g * OUTC + o1c];
        #pragma unroll
        for (int i = 0; i < 4; ++i) {
            const v4f s = L4[(r0 + i) * C4 + g];  // wave-uniform broadcast
            acc0[i] += s.x * w0.x + s.y * w0.y + s.z * w0.z + s.w * w0.w;
            acc1[i] += s.x * w1.x + s.y * w1.y + s.z * w1.z + s.w * w1.w;
        }
    }
    #pragma unroll
    for (int i = 0; i < 4; ++i) {
        const size_t v = (size_t)svrows[r0 + i];
        proj[v * OUTC + o0] = acc0[i];
        if (o1 < OUTC) proj[v * OUTC + o1] = acc1[i];
    }
}

// ---------------------------------------------------------------------------
// K4: out[n][o] = (1/128) * sum_j proj[label[n][j]][o] + bias[o]
// float2-vectorized: thread per (n, o/2). proj is L2/L3-hot right after K3.
// ---------------------------------------------------------------------------
#define OUT2 (OUTC / 2)
__global__ __launch_bounds__(256) void k_gather(const int* __restrict__ labels,
                                                const float2* __restrict__ proj2,
                                                const float2* __restrict__ bias2,
                                                float2* __restrict__ out2) {
    const int idx = blockIdx.x * 256 + threadIdx.x;
    if (idx >= NOUT * OUT2) return;
    const int n = idx / OUT2;
    const int o = idx - n * OUT2;
    const int* lab = labels + n * NLAB;
    float sx = 0.f, sy = 0.f;
    #pragma unroll
    for (int j = 0; j < NLAB; ++j) {
        const float2 p = proj2[(size_t)lab[j] * OUT2 + o];
        sx += p.x; sy += p.y;
    }
    const float2 b = bias2[o];
    out2[idx] = make_float2(sx * (1.0f / 128.0f) + b.x,
                            sy * (1.0f / 128.0f) + b.y);
}

// ---------------------------------------------------------------------------
// Fallback (only if ws too small): direct gather+reduce+conv per (b,l).
// ---------------------------------------------------------------------------
__global__ __launch_bounds__(128) void k_direct(const int* __restrict__ labels,
                                                const float* __restrict__ ft,
                                                const float* __restrict__ W,
                                                const float* __restrict__ bias,
                                                float* __restrict__ out) {
    __shared__ float4 sv[C4];
    const int n = blockIdx.x;
    const int tid = threadIdx.x;
    if (tid < C4) {
        float sx = 0.f, sy = 0.f, sz = 0.f, sw = 0.f;
        for (int j = 0; j < NLAB; ++j) {
            const int v = labels[n * NLAB + j];
            const float4* p = reinterpret_cast<const float4*>(
                ft + (size_t)v * FT_ROW + (size_t)tid * 4);
            #pragma unroll
            for (int k = 0; k < RTOT; ++k) {
                float4 t = p[k * C4];
                sx += t.x; sy += t.y; sz += t.z; sw += t.w;
            }
        }
        sv[tid] = make_float4(sx, sy, sz, sw);
    }
    __syncthreads();
    if (tid < OUTC) {
        const float4* w4 = reinterpret_cast<const float4*>(W + (size_t)tid * GLOVE);
        float a = 0.f;
        for (int c = 0; c < C4; ++c) {
            const float4 w = w4[c];
            const float4 s = sv[c];
            a += s.x * w.x + s.y * w.y + s.z * w.z + s.w * w.w;
        }
        out[(size_t)n * OUTC + tid] = a * (1.0f / 128.0f) + bias[tid];
    }
}

extern "C" void kernel_launch(void* const* d_in, const int* in_sizes, int n_in,
                              void* d_out, int out_size, void* d_ws, size_t ws_size,
                              hipStream_t stream) {
    const int*   labels = (const int*)d_in[0];    // [32,128,8] int32
    const float* ft     = (const float*)d_in[1];  // [20000,8,600] f32
    const float* W      = (const float*)d_in[2];  // [100,300] f32
    const float* bias   = (const float*)d_in[3];  // [100] f32
    float* out = (float*)d_out;                   // [32,128,100] f32

    // ws layout: [flags 80KB][count 16B][list 80KB][Wtg 120KB][proj 8MB]
    const size_t flags_bytes = (size_t)VOCAB * sizeof(int);
    const size_t count_bytes = 16;
    const size_t list_bytes  = (size_t)VOCAB * sizeof(int);
    const size_t wt_bytes    = (size_t)C4 * OUTC * sizeof(float4);
    const size_t proj_bytes  = (size_t)VOCAB * OUTC * sizeof(float);

    if (ws_size >= flags_bytes + count_bytes + list_bytes + wt_bytes + proj_bytes) {
        char* w = (char*)d_ws;
        int*    flags = (int*)w;                      w += flags_bytes;
        int*    count = (int*)w;                      w += count_bytes;
        int*    list  = (int*)w;                      w += list_bytes;
        float4* Wtg   = (float4*)w;                   w += wt_bytes;
        float*  proj  = (float*)w;

        const int nlabels = NOUT * NLAB; // 32768 (covers 7500 Wt items too)
        k_flags<<<(nlabels + 255) / 256, 256, 0, stream>>>(
            labels, flags, count, (const float4*)W, Wtg, nlabels);
        k_compact<<<(VOCAB + 255) / 256, 256, 0, stream>>>(flags, list, count);
        k_reduce_proj<<<(VOCAB + ROWS_A - 1) / ROWS_A, 256, 0, stream>>>(
            ft, Wtg, list, count, proj);
        k_gather<<<(NOUT * OUT2 + 255) / 256, 256, 0, stream>>>(
            labels, (const float2*)proj, (const float2*)bias, (float2*)out);
    } else {
        k_direct<<<NOUT, 128, 0, stream>>>(labels, ft, W, bias, out);
    }
}